// Round 5
// baseline (96.444 us; speedup 1.0000x reference)
//
#include <hip/hip_runtime.h>
#include <hip/hip_bf16.h>

#define SEQ 2048
#define DM  1024
#define NH  16
#define HD  64
#define BH  32
#define QB  32            // q rows per block (2 waves x 16)
#define KVB 32            // keys per tile
#define NT  (SEQ/KVB)     // 64 tiles
#define TILE_E (KVB*HD)   // 2048 bf16 per tile

#define KWS_OFF 0u        // [BH][NT][32 key][64 d]  swizzle baked (8-chunk XOR row&7)
#define VWS_OFF 4194304u  // [BH][NT][64 d][32 kv]   transposed, swizzle baked (4-chunk XOR row&3)

typedef __bf16 bf16x8 __attribute__((ext_vector_type(8)));
typedef __bf16 bf16x4 __attribute__((ext_vector_type(4)));
typedef float  f32x4  __attribute__((ext_vector_type(4)));

// K tile: [32 key][64 d], 128B rows: 16B-chunk XOR with row&7
__device__ __forceinline__ int swK(int row, int c) {
    return row * 64 + (c ^ ((row & 7) << 3));
}

// ---- prep: K/V fp32 -> bf16 head-split tiles, V transposed, swizzles pre-baked ----
__global__ __launch_bounds__(256) void psa_prep(
    const float* __restrict__ V, const float* __restrict__ K,
    __bf16* __restrict__ ws)
{
    const int blk = blockIdx.x;
    if (blk < 2048) {
        // K chunk (bh, t, key, cb): contents K[b][t*32+key][h*64+d0..+7], d0=((cb^(key&7))<<3)
        const int idx = blk * 256 + threadIdx.x;
        const int cb = idx & 7, key = (idx >> 3) & 31, t = (idx >> 8) & 63, bh = idx >> 14;
        const int b = bh >> 4, h = bh & 15;
        const int d0 = ((cb ^ (key & 7)) << 3);
        const float* src = K + ((size_t)(b * SEQ + t * 32 + key)) * DM + h * HD + d0;
        float4 a = *(const float4*)src, c = *(const float4*)(src + 4);
        bf16x8 o;
        o[0] = (__bf16)a.x; o[1] = (__bf16)a.y; o[2] = (__bf16)a.z; o[3] = (__bf16)a.w;
        o[4] = (__bf16)c.x; o[5] = (__bf16)c.y; o[6] = (__bf16)c.z; o[7] = (__bf16)c.w;
        *(bf16x8*)(ws + KWS_OFF + (size_t)idx * 8) = o;
    } else {
        // V chunk (bh, t, d, cb): contents V[b][t*32+kv0+j][h*64+d], kv0=((cb^(d&3))<<3)
        const int idx = (blk - 2048) * 256 + threadIdx.x;
        const int cb = idx & 3, d = (idx >> 2) & 63, t = (idx >> 8) & 63, bh = idx >> 14;
        const int b = bh >> 4, h = bh & 15;
        const int kv0 = ((cb ^ (d & 3)) << 3);
        const float* src = V + ((size_t)(b * SEQ + t * 32 + kv0)) * DM + h * HD + d;
        bf16x8 o;
#pragma unroll
        for (int j = 0; j < 8; ++j) o[j] = (__bf16)src[(size_t)j * DM];
        *(bf16x8*)(ws + VWS_OFF + (size_t)idx * 8) = o;
    }
}

// ---- main: 2 waves x 16 q-rows, KVB=32 DMA-staged tiles, 8 blocks/CU ----
__global__ __launch_bounds__(128, 4) void psa_main(
    const __bf16* __restrict__ ws, const float* __restrict__ Qg,
    float* __restrict__ Og)
{
    __shared__ __bf16 KT[2][TILE_E];      // 4 KB x2
    __shared__ __bf16 VT[2][TILE_E];      // 4 KB x2
    __shared__ __bf16 PT[2][16 * KVB];    // per-wave [16 q][32 k], 1 KB ea

    const int bid = blockIdx.x;
    const int swz = (bid & 7) * 256 + (bid >> 3);   // XCD-aware; 2048 % 8 == 0
    const int bh  = swz >> 6;                        // 4 bh per XCD -> 2MB K+V in L2
    const int qb  = swz & 63;
    const int b   = bh >> 4, h = bh & 15;
    const int tid = threadIdx.x;
    const int w   = tid >> 6;
    const int l   = tid & 63;
    const int c16 = l & 15;
    const int seg = l >> 4;
    const int q0  = qb * QB + w * 16;

    const __bf16* Kws = ws + KWS_OFF;
    const __bf16* Vws = ws + VWS_OFF;

    // Q fragment (B-layout: lane holds col q = q0+c16, k-dim d = ds*32+seg*8+j)
    bf16x8 qf[2];
#pragma unroll
    for (int ds = 0; ds < 2; ++ds) {
        const float* p = Qg + ((size_t)b * SEQ + q0 + c16) * DM + h * HD + ds * 32 + seg * 8;
        float4 a = *(const float4*)p, c = *(const float4*)(p + 4);
        bf16x8 o;
        o[0] = (__bf16)a.x; o[1] = (__bf16)a.y; o[2] = (__bf16)a.z; o[3] = (__bf16)a.w;
        o[4] = (__bf16)c.x; o[5] = (__bf16)c.y; o[6] = (__bf16)c.z; o[7] = (__bf16)c.w;
        qf[ds] = o;
    }

    f32x4 acc[4];
#pragma unroll
    for (int dt = 0; dt < 4; ++dt)
#pragma unroll
        for (int r = 0; r < 4; ++r) acc[dt][r] = 0.f;

    auto stage = [&](int bf, int t) {
        const size_t tb = ((size_t)bh * NT + t) * TILE_E;
#pragma unroll
        for (int i = 0; i < 2; ++i) {
            const int off = (i * 128 + tid) * 8;    // linear dest, lane x 16B
            __builtin_amdgcn_global_load_lds(
                (const __attribute__((address_space(1))) void*)(Kws + tb + off),
                (__attribute__((address_space(3))) void*)&KT[bf][off], 16, 0, 0);
            __builtin_amdgcn_global_load_lds(
                (const __attribute__((address_space(1))) void*)(Vws + tb + off),
                (__attribute__((address_space(3))) void*)&VT[bf][off], 16, 0, 0);
        }
    };

    stage(0, 0);
    __syncthreads();

    for (int t = 0; t < NT; ++t) {
        const int cur = t & 1;
        if (t + 1 < NT) stage(cur ^ 1, t + 1);   // prefetch next (drained at tile-end barrier)

        // ---- QK^T (swapped A=K, B=Q) -> silu -> PT (b64 writes, 4 keys/lane)
#pragma unroll
        for (int kt = 0; kt < 2; ++kt) {
            bf16x8 kf0 = *(const bf16x8*)&KT[cur][swK(kt * 16 + c16, seg * 8)];
            bf16x8 kf1 = *(const bf16x8*)&KT[cur][swK(kt * 16 + c16, 32 + seg * 8)];
            f32x4 s;
#pragma unroll
            for (int r = 0; r < 4; ++r) s[r] = 0.f;
            __builtin_amdgcn_s_setprio(1);
            s = __builtin_amdgcn_mfma_f32_16x16x32_bf16(kf0, qf[0], s, 0, 0, 0);
            s = __builtin_amdgcn_mfma_f32_16x16x32_bf16(kf1, qf[1], s, 0, 0, 0);
            __builtin_amdgcn_s_setprio(0);
            bf16x4 pw;
#pragma unroll
            for (int r = 0; r < 4; ++r) {
                float x = s[r];
                float e = __expf(-x);
                pw[r] = (__bf16)(x * __builtin_amdgcn_rcpf(1.f + e));
            }
            // PT [16 q][32 k], 64B rows: 16B-chunk XOR row&3, preserve 8B sub-offset
            const int col = kt * 16 + seg * 4;
            const int sc  = (col & 7) | ((((col >> 3) ^ (c16 & 3)) & 3) << 3);
            *(bf16x4*)&PT[w][c16 * 32 + sc] = pw;
        }

        // ---- out += P * V  (A = P row q, B = V^T col d)
        bf16x8 pa = *(const bf16x8*)&PT[w][c16 * 32 + ((seg ^ (c16 & 3)) << 3)];
        __builtin_amdgcn_s_setprio(1);
#pragma unroll
        for (int dt = 0; dt < 4; ++dt) {
            const int vrow = dt * 16 + c16;
            bf16x8 vf = *(const bf16x8*)&VT[cur][vrow * 32 + ((seg ^ (vrow & 3)) << 3)];
            acc[dt] = __builtin_amdgcn_mfma_f32_16x16x32_bf16(pa, vf, acc[dt], 0, 0, 0);
        }
        __builtin_amdgcn_s_setprio(0);

        __syncthreads();
    }

    // ---- epilogue: D layout row q = seg*4+r, col d = dt*16+c16
    float* op = Og + ((size_t)b * SEQ + q0) * DM + h * HD;
#pragma unroll
    for (int dt = 0; dt < 4; ++dt)
#pragma unroll
        for (int r = 0; r < 4; ++r)
            op[(size_t)(seg * 4 + r) * DM + dt * 16 + c16] = acc[dt][r];
}

extern "C" void kernel_launch(void* const* d_in, const int* in_sizes, int n_in,
                              void* d_out, int out_size, void* d_ws, size_t ws_size,
                              hipStream_t stream) {
    const float* v = (const float*)d_in[0];
    const float* k = (const float*)d_in[1];
    const float* q = (const float*)d_in[2];
    float* out = (float*)d_out;
    __bf16* ws = (__bf16*)d_ws;
    (void)in_sizes; (void)n_in; (void)out_size; (void)ws_size;

    psa_prep<<<dim3(4096), dim3(256), 0, stream>>>(v, k, ws);
    psa_main<<<dim3(BH * (SEQ / QB)), dim3(128), 0, stream>>>(ws, q, out);
}

// Round 6
// 83.110 us; speedup vs baseline: 1.1604x; 1.1604x over previous
//
#include <hip/hip_runtime.h>
#include <hip/hip_bf16.h>

#define SEQ 2048
#define DM  1024
#define NH  16
#define HD  64
#define BH  32
#define QB  64            // q rows per block (4 waves x 16)
#define KVB 64
#define NT  (SEQ/KVB)     // 32 tiles
#define TILE_E (KVB*HD)   // 4096 bf16 per tile

#define KWS_OFF 0u        // [BH][NT][64 key][64 d]  swizzle baked
#define VWS_OFF 4194304u  // [BH][NT][64 d][64 kv]   transposed, swizzle baked

typedef __bf16 bf16x8 __attribute__((ext_vector_type(8)));
typedef __bf16 bf16x4 __attribute__((ext_vector_type(4)));
typedef float  f32x4  __attribute__((ext_vector_type(4)));

#define LOG2E 1.44269504088896f

// swizzled element offset in a [R][64] bf16 tile (row stride 128B)
__device__ __forceinline__ int sw64(int row, int c) {
    return row * 64 + (c ^ ((row & 7) << 3));
}

// ---- prep: K/V fp32 -> bf16 head-split tiles, V transposed, swizzle pre-baked ----
__global__ __launch_bounds__(256) void psa_prep(
    const float* __restrict__ V, const float* __restrict__ K,
    __bf16* __restrict__ ws)
{
    const int blk = blockIdx.x;
    if (blk < 2048) {
        // K chunk (bh, t, key, cb): contents K[b][t*64+key][h*64+d0..+7], d0=((cb^(key&7))<<3)
        const int idx = blk * 256 + threadIdx.x;
        const int cb = idx & 7, key = (idx >> 3) & 63, t = (idx >> 9) & 31, bh = idx >> 14;
        const int b = bh >> 4, h = bh & 15;
        const int d0 = ((cb ^ (key & 7)) << 3);
        const float* src = K + ((size_t)(b * SEQ + t * 64 + key)) * DM + h * HD + d0;
        float4 a = *(const float4*)src, c = *(const float4*)(src + 4);
        bf16x8 o;
        o[0] = (__bf16)a.x; o[1] = (__bf16)a.y; o[2] = (__bf16)a.z; o[3] = (__bf16)a.w;
        o[4] = (__bf16)c.x; o[5] = (__bf16)c.y; o[6] = (__bf16)c.z; o[7] = (__bf16)c.w;
        *(bf16x8*)(ws + KWS_OFF + (size_t)idx * 8) = o;
    } else {
        // V chunk (bh, t, d, cb): contents V[b][t*64+ks0+j][h*64+d], ks0=((cb^(d&7))<<3)
        const int idx = (blk - 2048) * 256 + threadIdx.x;
        const int cb = idx & 7, d = (idx >> 3) & 63, t = (idx >> 9) & 31, bh = idx >> 14;
        const int b = bh >> 4, h = bh & 15;
        const int ks0 = ((cb ^ (d & 7)) << 3);
        const float* src = V + ((size_t)(b * SEQ + t * 64 + ks0)) * DM + h * HD + d;
        bf16x8 o;
#pragma unroll
        for (int j = 0; j < 8; ++j) o[j] = (__bf16)src[(size_t)j * DM];
        *(bf16x8*)(ws + VWS_OFF + (size_t)idx * 8) = o;
    }
}

// ---- main: 4 waves x 16 q-rows, DMA-staged K/V, 4 blocks/CU ----
__global__ __launch_bounds__(256, 4) void psa_main(
    const __bf16* __restrict__ ws, const float* __restrict__ Qg,
    float* __restrict__ Og)
{
    __shared__ __bf16 KT[2][TILE_E];      // 8 KB x2
    __shared__ __bf16 VT[2][TILE_E];      // 8 KB x2
    __shared__ __bf16 PT[4][16 * KVB];    // per-wave [16 q][64 k] swizzled, 2 KB ea

    const int bid = blockIdx.x;
    const int swz = (bid & 7) * 128 + (bid >> 3);   // XCD-aware; 1024 % 8 == 0
    const int bh  = swz >> 5;
    const int qb  = swz & 31;
    const int b   = bh >> 4, h = bh & 15;
    const int tid = threadIdx.x;
    const int w   = tid >> 6;
    const int l   = tid & 63;
    const int c16 = l & 15;
    const int seg = l >> 4;
    const int q0  = qb * QB + w * 16;

    const __bf16* Kws = ws + KWS_OFF;
    const __bf16* Vws = ws + VWS_OFF;

    // Q fragment (B-layout: lane holds col q = q0+c16, k-dim d = ds*32+seg*8+j)
    bf16x8 qf[2];
#pragma unroll
    for (int ds = 0; ds < 2; ++ds) {
        const float* p = Qg + ((size_t)b * SEQ + q0 + c16) * DM + h * HD + ds * 32 + seg * 8;
        float4 a = *(const float4*)p, c = *(const float4*)(p + 4);
        bf16x8 o;
        o[0] = (__bf16)a.x; o[1] = (__bf16)a.y; o[2] = (__bf16)a.z; o[3] = (__bf16)a.w;
        o[4] = (__bf16)c.x; o[5] = (__bf16)c.y; o[6] = (__bf16)c.z; o[7] = (__bf16)c.w;
        qf[ds] = o;
    }

    f32x4 acc[4];
#pragma unroll
    for (int dt = 0; dt < 4; ++dt)
#pragma unroll
        for (int r = 0; r < 4; ++r) acc[dt][r] = 0.f;

    auto stage = [&](int bf, int t) {
        const size_t tb = ((size_t)bh * NT + t) * TILE_E;
#pragma unroll
        for (int i = 0; i < 2; ++i) {
            const int ch  = w * 2 + i;              // 8 x 1KB chunks per tensor
            const int off = ch * 512 + l * 8;
            __builtin_amdgcn_global_load_lds(
                (const __attribute__((address_space(1))) void*)(Kws + tb + off),
                (__attribute__((address_space(3))) void*)&KT[bf][ch * 512], 16, 0, 0);
            __builtin_amdgcn_global_load_lds(
                (const __attribute__((address_space(1))) void*)(Vws + tb + off),
                (__attribute__((address_space(3))) void*)&VT[bf][ch * 512], 16, 0, 0);
        }
    };

    stage(0, 0);
    __syncthreads();

    for (int t = 0; t < NT; ++t) {
        const int cur = t & 1;
        if (t + 1 < NT) stage(cur ^ 1, t + 1);   // prefetch next (drained at tile-end barrier)

        // ---- QK^T (swapped A=K, B=Q) -> silu -> PT (b64 writes, 4 keys/lane)
#pragma unroll
        for (int kt = 0; kt < 4; ++kt) {
            bf16x8 kf0 = *(const bf16x8*)&KT[cur][sw64(kt * 16 + c16, seg * 8)];
            bf16x8 kf1 = *(const bf16x8*)&KT[cur][sw64(kt * 16 + c16, 32 + seg * 8)];
            f32x4 s;
#pragma unroll
            for (int r = 0; r < 4; ++r) s[r] = 0.f;
            __builtin_amdgcn_s_setprio(1);
            s = __builtin_amdgcn_mfma_f32_16x16x32_bf16(kf0, qf[0], s, 0, 0, 0);
            s = __builtin_amdgcn_mfma_f32_16x16x32_bf16(kf1, qf[1], s, 0, 0, 0);
            __builtin_amdgcn_s_setprio(0);
            bf16x4 pw;
#pragma unroll
            for (int r = 0; r < 4; ++r) {
                float x = s[r];
                // silu(x) = x * rcp(1 + 2^(-x*log2e))  — raw v_exp_f32 (HW exp2),
                // avoids __ocml_exp_f32 range-reduction expansion (~15 VALU/elem)
                float t2;
                asm("v_exp_f32 %0, %1" : "=v"(t2) : "v"(x * -LOG2E));
                pw[r] = (__bf16)(x * __builtin_amdgcn_rcpf(1.f + t2));
            }
            // D layout: q-col = c16, key = kt*16 + seg*4 + r
            *(bf16x4*)&PT[w][sw64(c16, kt * 16 + seg * 4)] = pw;
        }

        // ---- out += P * V  (A = P row q=c16, B = V^T col d=dt*16+c16)
#pragma unroll
        for (int kc = 0; kc < 2; ++kc) {
            bf16x8 pa = *(const bf16x8*)&PT[w][sw64(c16, kc * 32 + seg * 8)];
            __builtin_amdgcn_s_setprio(1);
#pragma unroll
            for (int dt = 0; dt < 4; ++dt) {
                bf16x8 vf = *(const bf16x8*)&VT[cur][sw64(dt * 16 + c16, kc * 32 + seg * 8)];
                acc[dt] = __builtin_amdgcn_mfma_f32_16x16x32_bf16(pa, vf, acc[dt], 0, 0, 0);
            }
            __builtin_amdgcn_s_setprio(0);
        }

        __syncthreads();
    }

    // ---- epilogue: D layout row q = seg*4+r, col d = dt*16+c16
    float* op = Og + ((size_t)b * SEQ + q0) * DM + h * HD;
#pragma unroll
    for (int dt = 0; dt < 4; ++dt)
#pragma unroll
        for (int r = 0; r < 4; ++r)
            op[(size_t)(seg * 4 + r) * DM + dt * 16 + c16] = acc[dt][r];
}

extern "C" void kernel_launch(void* const* d_in, const int* in_sizes, int n_in,
                              void* d_out, int out_size, void* d_ws, size_t ws_size,
                              hipStream_t stream) {
    const float* v = (const float*)d_in[0];
    const float* k = (const float*)d_in[1];
    const float* q = (const float*)d_in[2];
    float* out = (float*)d_out;
    __bf16* ws = (__bf16*)d_ws;
    (void)in_sizes; (void)n_in; (void)out_size; (void)ws_size;

    psa_prep<<<dim3(4096), dim3(256), 0, stream>>>(v, k, ws);
    psa_main<<<dim3(BH * (SEQ / QB)), dim3(256), 0, stream>>>(ws, q, out);
}